// Round 6
// baseline (377.604 us; speedup 1.0000x reference)
//
#include <hip/hip_runtime.h>
#include <hip/hip_bf16.h>

#define EMBED  2048
#define SEQ    2048
#define BATCH  2
#define NHEADS 16
#define HDIM   128
#define QKVC   (3*EMBED)    // 6144
#define ROWS   (BATCH*SEQ)  // 4096

typedef __attribute__((ext_vector_type(8))) short bf16x8;
typedef __attribute__((ext_vector_type(4))) float f32x4;
typedef __attribute__((ext_vector_type(16))) float f32x16;

typedef const __attribute__((address_space(1))) void* gptr1_t;
typedef __attribute__((address_space(3))) void* lptr3_t;

__device__ __forceinline__ void gld16(const unsigned short* g, unsigned short* l) {
  __builtin_amdgcn_global_load_lds((gptr1_t)g, (lptr3_t)l, 16, 0, 0);
}

__device__ __forceinline__ unsigned short f2bf(float f) {
  unsigned int x = __float_as_uint(f);
  unsigned int r = (x + 0x7fffu + ((x >> 16) & 1u)) >> 16;
  return (unsigned short)r;
}

// ---------------- fused prep: cast x -> bf16 AND both W transposes ----------------
__global__ __launch_bounds__(256)
void prep_kernel(const float* __restrict__ x,
                 const float* __restrict__ Wqkv,
                 const float* __restrict__ Wout,
                 unsigned short* __restrict__ xb,
                 unsigned short* __restrict__ wqkvT,
                 unsigned short* __restrict__ woutT) {
  __shared__ float tile[32][33];
  const int bid = blockIdx.x;
  if (bid < 8192) {
    int i = bid * 256 + threadIdx.x;
    float4 v = reinterpret_cast<const float4*>(x)[i];
    ushort4 o;
    o.x = f2bf(v.x); o.y = f2bf(v.y); o.z = f2bf(v.z); o.w = f2bf(v.w);
    reinterpret_cast<ushort4*>(xb)[i] = o;
    return;
  }
  const float* in; unsigned short* out; int C, bx, by;
  if (bid < 8192 + 12288) {
    int j = bid - 8192;  bx = j % 192; by = j / 192;  in = Wqkv; out = wqkvT; C = QKVC;
  } else {
    int j = bid - 20480; bx = j % 64;  by = j / 64;   in = Wout; out = woutT; C = EMBED;
  }
  const int R = EMBED;
  int tx = threadIdx.x & 31, ty = threadIdx.x >> 5;   // 32 x 8
  int c0 = bx * 32, r0 = by * 32;
  #pragma unroll
  for (int i = 0; i < 32; i += 8)
    tile[ty + i][tx] = in[(size_t)(r0 + ty + i) * C + c0 + tx];
  __syncthreads();
  #pragma unroll
  for (int i = 0; i < 32; i += 8)
    out[(size_t)(c0 + ty + i) * R + r0 + tx] = f2bf(tile[tx][ty + i]);
}

// ---------------- 128x128 MFMA GEMM ----------
// MODE 1: f32 out, row stride N (out-projection)
// MODE 2: V-only QKV third: BT/bias pre-offset by 4096; output transposed into vt
template<int MODE>
__global__ __launch_bounds__(256)
void gemm_kernel(const unsigned short* __restrict__ A,
                 const unsigned short* __restrict__ BT,
                 const float* __restrict__ bias,
                 unsigned short* __restrict__ outb,
                 unsigned short* __restrict__ vt,
                 float* __restrict__ outf,
                 int M, int N, int K) {
  __shared__ unsigned short As[2 * 128 * 32];   // two BK=32 sub-tiles
  __shared__ unsigned short Bs[2 * 128 * 32];
  const int t = threadIdx.x;
  const int lane = t & 63, wave = t >> 6;
  const int l31 = lane & 31, hl = lane >> 5;
  const int wm = wave >> 1, wn = wave & 1;
  const int m0 = blockIdx.y * 128, n0 = blockIdx.x * 128;

  f32x16 acc[2][2] = {};

  int aoff[2][4], boff[2][4];
  #pragma unroll
  for (int i = 0; i < 2; ++i) {
    int m = wm * 64 + i * 32 + l31;
    int pm = ((m >> 2) ^ m) & 3;
    int n = wn * 64 + i * 32 + l31;
    int pn = ((n >> 2) ^ n) & 3;
    #pragma unroll
    for (int s4 = 0; s4 < 4; ++s4) {
      int st = s4 >> 1, c = (s4 & 1) * 2 + hl;
      aoff[i][s4] = st * 4096 + (m * 4 + (c ^ pm)) * 8;
      boff[i][s4] = st * 4096 + (n * 4 + (c ^ pn)) * 8;
    }
  }
  int ldso[4];
  const unsigned short* Ag[4];
  const unsigned short* Bg[4];
  #pragma unroll
  for (int i = 0; i < 4; ++i) {
    int cc = i * 256 + t;
    int st = cc >> 9, w = cc & 511;
    int r = w >> 2, s = w & 3;
    int d = s ^ (((r >> 2) ^ r) & 3);
    ldso[i] = st * 4096 + w * 8;
    Ag[i] = A  + (size_t)(m0 + r) * K + st * 32 + d * 8;
    Bg[i] = BT + (size_t)(n0 + r) * K + st * 32 + d * 8;
  }

  for (int k0 = 0; k0 < K; k0 += 64) {
    #pragma unroll
    for (int i = 0; i < 4; ++i) gld16(Ag[i] + k0, &As[ldso[i]]);
    #pragma unroll
    for (int i = 0; i < 4; ++i) gld16(Bg[i] + k0, &Bs[ldso[i]]);
    __syncthreads();
    #pragma unroll
    for (int s4 = 0; s4 < 4; ++s4) {
      bf16x8 a0 = *(const bf16x8*)&As[aoff[0][s4]];
      bf16x8 a1 = *(const bf16x8*)&As[aoff[1][s4]];
      bf16x8 b0 = *(const bf16x8*)&Bs[boff[0][s4]];
      bf16x8 b1 = *(const bf16x8*)&Bs[boff[1][s4]];
      acc[0][0] = __builtin_amdgcn_mfma_f32_32x32x16_bf16(a0, b0, acc[0][0], 0, 0, 0);
      acc[0][1] = __builtin_amdgcn_mfma_f32_32x32x16_bf16(a0, b1, acc[0][1], 0, 0, 0);
      acc[1][0] = __builtin_amdgcn_mfma_f32_32x32x16_bf16(a1, b0, acc[1][0], 0, 0, 0);
      acc[1][1] = __builtin_amdgcn_mfma_f32_32x32x16_bf16(a1, b1, acc[1][1], 0, 0, 0);
    }
    __syncthreads();
  }

  #pragma unroll
  for (int i = 0; i < 2; ++i) {
    int rowb = m0 + wm * 64 + i * 32 + 4 * hl;
    #pragma unroll
    for (int j = 0; j < 2; ++j) {
      int col = n0 + wn * 64 + j * 32 + l31;
      float bv = bias[col];
      if (MODE == 1) {
        #pragma unroll
        for (int g = 0; g < 4; ++g)
          #pragma unroll
          for (int rr = 0; rr < 4; ++rr)
            outf[(size_t)(rowb + 8 * g + rr) * N + col] = acc[i][j][4 * g + rr] + bv;
      } else {
        // MODE 2: V region (BT/bias pre-offset): write transposed into vt
        int hd = col;
        int b = rowb >> 11;
        int sbase = rowb & 2047;
        #pragma unroll
        for (int g = 0; g < 4; ++g) {
          ushort4 w;
          w.x = f2bf(acc[i][j][4 * g + 0] + bv);
          w.y = f2bf(acc[i][j][4 * g + 1] + bv);
          w.z = f2bf(acc[i][j][4 * g + 2] + bv);
          w.w = f2bf(acc[i][j][4 * g + 3] + bv);
          *(ushort4*)&vt[(((size_t)(b << 11) + hd) << 11) + sbase + 8 * g] = w;
        }
      }
    }
  }
}

// ---------------- 256x256 8-phase MFMA GEMM (Q|K part) ------
#define FENCE256 asm volatile("" ::: "memory")
#define BAR256 do { FENCE256; __builtin_amdgcn_s_barrier(); FENCE256; } while (0)

#define STAGE_A256(BUF, H, KT) do { if ((KT) < NT) { \
    gld16(Asrc[0] + (H)*128*K + (KT)*64, &As[BUF][(H)*8192 + sdst0]); \
    gld16(Asrc[1] + (H)*128*K + (KT)*64, &As[BUF][(H)*8192 + sdst1]); } } while (0)
#define STAGE_B256(BUF, H, KT) do { if ((KT) < NT) { \
    gld16(Bsrc[0] + (H)*128*K + (KT)*64, &Bs[BUF][(H)*8192 + sdst0]); \
    gld16(Bsrc[1] + (H)*128*K + (KT)*64, &Bs[BUF][(H)*8192 + sdst1]); } } while (0)

#define READ_A256(BUF, MH) do { _Pragma("unroll") \
  for (int mf = 0; mf < 4; ++mf) { \
    av[mf][0] = *(const bf16x8*)&As[BUF][arow0 + (MH)*4096 + mf*1024 + ck0]; \
    av[mf][1] = *(const bf16x8*)&As[BUF][arow0 + (MH)*4096 + mf*1024 + ck1]; } } while (0)
#define READ_B256(BUF, NH, DST) do { _Pragma("unroll") \
  for (int nf = 0; nf < 2; ++nf) { \
    DST[nf][0] = *(const bf16x8*)&Bs[BUF][brow0 + (NH)*2048 + nf*1024 + ck0]; \
    DST[nf][1] = *(const bf16x8*)&Bs[BUF][brow0 + (NH)*2048 + nf*1024 + ck1]; } } while (0)

#define MFMA_Q256(MH, NH, B_) do { \
  __builtin_amdgcn_s_setprio(1); \
  _Pragma("unroll") \
  for (int mf = 0; mf < 4; ++mf) { \
    _Pragma("unroll") \
    for (int nf = 0; nf < 2; ++nf) { \
      f32x4 c = acc[(MH)*4 + mf][(NH)*2 + nf]; \
      c = __builtin_amdgcn_mfma_f32_16x16x32_bf16(av[mf][0], B_[nf][0], c, 0, 0, 0); \
      c = __builtin_amdgcn_mfma_f32_16x16x32_bf16(av[mf][1], B_[nf][1], c, 0, 0, 0); \
      acc[(MH)*4 + mf][(NH)*2 + nf] = c; } } \
  __builtin_amdgcn_s_setprio(0); } while (0)

#define VMCNT256(LAST) do { \
  if (LAST) asm volatile("s_waitcnt vmcnt(0)" ::: "memory"); \
  else      asm volatile("s_waitcnt vmcnt(4)" ::: "memory"); } while (0)

__global__ __launch_bounds__(512, 2)
void gemm256_kernel(const unsigned short* __restrict__ A,
                    const unsigned short* __restrict__ BT,
                    const float* __restrict__ bias,
                    unsigned short* __restrict__ outb,
                    unsigned short* __restrict__ vt,
                    int M, int N, int K) {
  __shared__ __align__(16) unsigned short As[2][16384];
  __shared__ __align__(16) unsigned short Bs[2][16384];
  const int t = threadIdx.x;
  const int lane = t & 63, wave = t >> 6;
  const int l16 = lane & 15, quad = (lane >> 4) & 3;
  const int wm = wave >> 2, wn = wave & 3;

  const int nwg = (int)gridDim.x;
  int swz = (int)blockIdx.x;
  if ((nwg & 7) == 0) swz = (swz & 7) * (nwg >> 3) + (swz >> 3);
  const int ntiles = N >> 8;
  const int mt = swz / ntiles, nt = swz % ntiles;
  const int m0 = mt << 8, n0 = nt << 8;

  const int NT = K >> 6;   // K-tiles of 64 (32)
  const int NI = NT >> 1;  // 8-phase iterations (16)

  f32x4 acc[8][4] = {};
  bf16x8 av[4][2], bv0[2][2], bv1[2][2];

  const unsigned short* Asrc[2];
  const unsigned short* Bsrc[2];
  int sdst0, sdst1;
  {
    int cc0 = t, cc1 = 512 + t;
    int r0 = cc0 >> 3, c0 = cc0 & 7;
    int r1 = cc1 >> 3, c1 = cc1 & 7;
    Asrc[0] = A  + (size_t)(m0 + r0) * K + ((c0 ^ (r0 & 7)) << 3);
    Asrc[1] = A  + (size_t)(m0 + r1) * K + ((c1 ^ (r1 & 7)) << 3);
    Bsrc[0] = BT + (size_t)(n0 + r0) * K + ((c0 ^ (r0 & 7)) << 3);
    Bsrc[1] = BT + (size_t)(n0 + r1) * K + ((c1 ^ (r1 & 7)) << 3);
    sdst0 = cc0 << 3;
    sdst1 = cc1 << 3;
  }

  const int ck0 = ((quad) ^ (l16 & 7)) << 3;       // k-sub 0 chunk
  const int ck1 = ((4 + quad) ^ (l16 & 7)) << 3;   // k-sub 1 chunk
  const int arow0 = (wm * 128 + l16) * 64;
  const int brow0 = (wn * 64 + l16) * 64;

  STAGE_A256(0, 0, 0); STAGE_A256(0, 1, 0);
  STAGE_B256(0, 0, 0); STAGE_B256(0, 1, 0);
  STAGE_B256(1, 0, 1); STAGE_B256(1, 1, 1);
  asm volatile("s_waitcnt vmcnt(4)" ::: "memory");
  BAR256;

  for (int it = 0; it < NI; ++it) {
    const int kt1 = 2 * it + 1, ktA = 2 * it + 2, ktB = 2 * it + 3;
    const bool last = (it == NI - 1);

    READ_A256(0, 0); READ_B256(0, 0, bv0);
    STAGE_A256(1, 0, kt1);
    BAR256; MFMA_Q256(0, 0, bv0); BAR256;
    READ_B256(0, 1, bv1);
    STAGE_A256(1, 1, kt1);
    BAR256; MFMA_Q256(0, 1, bv1); BAR256;
    READ_A256(0, 1);
    STAGE_B256(0, 0, ktA);
    BAR256; MFMA_Q256(1, 1, bv1); BAR256;
    STAGE_B256(0, 1, ktA);
    BAR256; MFMA_Q256(1, 0, bv0);
    VMCNT256(last);
    BAR256;
    READ_A256(1, 0); READ_B256(1, 0, bv0);
    STAGE_A256(0, 0, ktA);
    BAR256; MFMA_Q256(0, 0, bv0); BAR256;
    READ_B256(1, 1, bv1);
    STAGE_A256(0, 1, ktA);
    BAR256; MFMA_Q256(0, 1, bv1); BAR256;
    READ_A256(1, 1);
    STAGE_B256(1, 0, ktB);
    BAR256; MFMA_Q256(1, 1, bv1); BAR256;
    STAGE_B256(1, 1, ktB);
    BAR256; MFMA_Q256(1, 0, bv0);
    VMCNT256(last);
    BAR256;
  }

  // epilogue; Q region pre-scaled by 1/sqrt(128)*log2(e)
  const float scl = (n0 < EMBED) ? (0.08838834764831845f * 1.4426950408889634f) : 1.0f;
  #pragma unroll
  for (int mf = 0; mf < 8; ++mf) {
    const int row = m0 + wm * 128 + (mf >> 2) * 64 + (mf & 3) * 16 + quad * 4;
    #pragma unroll
    for (int nf = 0; nf < 4; ++nf) {
      const int col = n0 + wn * 64 + (nf >> 1) * 32 + (nf & 1) * 16 + l16;
      const float bv = bias[col];
      #pragma unroll
      for (int r = 0; r < 4; ++r)
        outb[(size_t)(row + r) * 4096 + col] = f2bf((acc[mf][nf][r] + bv) * scl);
    }
  }
  (void)vt; (void)M;
}

// ---------------- flash attention (S^T form, double-buffered K/V) ----------------
// Round-6: 2 blocks/CU. Ps shrunk to stride-64 with 16B-slot XOR swizzle
// (slot ^= l16&7, same involution on write and read) -> LDS = 32K+32K+16K =
// 81920 B exactly; 2 x 81920 = 163840 = full 160 KiB/CU -> 2 blocks/CU.
// Grid (32,16): one 128-row q-tile per block; qt(y) = y<8 ? 15-y : y-8 so
// co-resident pairs (id, id+256) sum to constant work (balanced), big tiles first.
__global__ __launch_bounds__(512, 4)
void attn_kernel(const unsigned short* __restrict__ qk,   // [4096][4096] Q|K bf16
                 const unsigned short* __restrict__ vt,   // [32*128][2048] V^T bf16
                 unsigned short* __restrict__ outb) {     // [4096][2048] bf16
  __shared__ unsigned short Ks[2][64 * 128];
  __shared__ unsigned short Vs[2][64 * 128];
  __shared__ unsigned short Ps[8][16 * 64];
  const int t = threadIdx.x;
  const int lane = t & 63, wave = t >> 6;
  const int quad = lane >> 4, l16 = lane & 15;
  const int bh = blockIdx.x;
  const int y = blockIdx.y;
  const int qt = (y < 8) ? (15 - y) : (y - 8);    // balanced co-residency mapping
  const int b = bh >> 4, h = bh & 15;
  const size_t rowbase = (size_t)b * SEQ;
  const int hq = h * HDIM;
  const unsigned short* vbase = vt + ((size_t)bh * HDIM) * SEQ;

  const int qw0 = qt * 128 + wave * 16;
  const int jmax = 2 * qt + 1;                    // KV tiles of 64: 0..jmax

  bf16x8 qf[4];
  {
    const unsigned short* qrow = qk + (size_t)(rowbase + qw0 + l16) * 4096 + hq + quad * 8;
    #pragma unroll
    for (int s = 0; s < 4; ++s) qf[s] = *(const bf16x8*)(qrow + s * 32);
  }

  f32x4 o[8] = {};
  float mrow = -1e30f, lrow = 0.f;

  // prologue: stage tile 0 into buffer 0 (1024 chunks over 512 threads)
  #pragma unroll
  for (int i = 0; i < 2; ++i) {
    int cc = i * 512 + t;
    int kv = cc >> 4, sc = cc & 15;
    int dc = sc ^ (kv & 15);
    gld16(qk + (size_t)(rowbase + kv) * 4096 + EMBED + hq + dc * 8, &Ks[0][cc * 8]);
  }
  #pragma unroll
  for (int i = 0; i < 2; ++i) {
    int cc = i * 512 + t;
    int d = cc >> 3, c = cc & 7;
    int dc = c ^ (d & 7);
    gld16(vbase + (size_t)d * SEQ + dc * 8, &Vs[0][cc * 8]);
  }

  for (int j = 0; j <= jmax; ++j) {
    const int cur = j & 1;
    __syncthreads();   // buf[cur] ready; all reads of buf[cur^1] complete

    if (j < jmax) {    // prefetch tile j+1, overlapped with compute below
      const int kv1 = (j + 1) * 64;
      #pragma unroll
      for (int i = 0; i < 2; ++i) {
        int cc = i * 512 + t;
        int kv = cc >> 4, sc = cc & 15;
        int dc = sc ^ (kv & 15);
        gld16(qk + (size_t)(rowbase + kv1 + kv) * 4096 + EMBED + hq + dc * 8, &Ks[cur ^ 1][cc * 8]);
      }
      #pragma unroll
      for (int i = 0; i < 2; ++i) {
        int cc = i * 512 + t;
        int d = cc >> 3, c = cc & 7;
        int dc = c ^ (d & 7);
        gld16(vbase + (size_t)d * SEQ + kv1 + dc * 8, &Vs[cur ^ 1][cc * 8]);
      }
    }

    const int kv0 = j * 64;
    if (kv0 > qw0 + 15) continue;   // wave-uniform: tile fully masked for this wave
                                    // (no barriers below -> safe divergence)

    f32x4 sacc[4] = {};
    #pragma unroll
    for (int nb = 0; nb < 4; ++nb) {
      int kvr = nb * 16 + l16;
      #pragma unroll
      for (int ks = 0; ks < 4; ++ks) {
        int dc2 = (ks * 4 + quad) ^ (kvr & 15);
        bf16x8 kb = *(const bf16x8*)&Ks[cur][(kvr * 16 + dc2) * 8];
        sacc[nb] = __builtin_amdgcn_mfma_f32_16x16x32_bf16(kb, qf[ks], sacc[nb], 0, 0, 0);
      }
    }

    float p[4][4];
    float smax = -1e30f;
    if (kv0 + 63 > qw0) {           // diagonal region for this wave: apply causal mask
      const int qg = qw0 + l16;
      #pragma unroll
      for (int nb = 0; nb < 4; ++nb)
        #pragma unroll
        for (int r = 0; r < 4; ++r) {
          float v = sacc[nb][r];
          if ((kv0 + nb * 16 + quad * 4 + r) > qg) v = -1e30f;
          p[nb][r] = v;
          smax = fmaxf(smax, v);
        }
    } else {
      #pragma unroll
      for (int nb = 0; nb < 4; ++nb)
        #pragma unroll
        for (int r = 0; r < 4; ++r) {
          float v = sacc[nb][r];
          p[nb][r] = v;
          smax = fmaxf(smax, v);
        }
    }
    smax = fmaxf(smax, __shfl_xor(smax, 16));
    smax = fmaxf(smax, __shfl_xor(smax, 32));

    const float mold = mrow;
    const unsigned long long grew = __ballot(smax > mold);
    const float mnew = fmaxf(mold, smax);
    mrow = mnew;

    float rs = 0.f;
    #pragma unroll
    for (int nb = 0; nb < 4; ++nb)
      #pragma unroll
      for (int r = 0; r < 4; ++r) {
        float pv = exp2f(p[nb][r] - mnew);
        p[nb][r] = pv;
        rs += pv;
      }
    rs += __shfl_xor(rs, 16);
    rs += __shfl_xor(rs, 32);

    // Ps: stride 64 shorts, 16B-slot XOR swizzle (slot ^= l16&7, bijective)
    unsigned short* pw = &Ps[wave][0];
    #pragma unroll
    for (int nb = 0; nb < 4; ++nb) {
      __hip_bfloat162 lo = __float22bfloat162_rn(make_float2(p[nb][0], p[nb][1]));
      __hip_bfloat162 hi = __float22bfloat162_rn(make_float2(p[nb][2], p[nb][3]));
      ushort4 w;
      w.x = *(unsigned short*)&lo.x; w.y = *(unsigned short*)&lo.y;
      w.z = *(unsigned short*)&hi.x; w.w = *(unsigned short*)&hi.y;
      // logical col (shorts) = nb*16 + quad*4; slot = nb*2 + (quad>>1)
      *(ushort4*)&pw[l16 * 64 + (((nb * 2 + (quad >> 1)) ^ (l16 & 7)) << 3) + (quad & 1) * 4] = w;
    }

    if (grew) {   // wave-uniform: some q-row's max increased -> rescale O and lrow
      float alpha = exp2f(mold - mnew);   // ==1 for rows that didn't grow
      lrow = lrow * alpha + rs;
      #pragma unroll
      for (int r = 0; r < 4; ++r) {
        float av = __shfl(alpha, quad * 4 + r, 16);
        #pragma unroll
        for (int db = 0; db < 8; ++db) o[db][r] *= av;
      }
    } else {
      lrow += rs;
    }

    asm volatile("s_waitcnt lgkmcnt(0)" ::: "memory");
    bf16x8 pa[2];
    #pragma unroll
    for (int ks2 = 0; ks2 < 2; ++ks2)
      pa[ks2] = *(const bf16x8*)&pw[l16 * 64 + (((ks2 * 4 + quad) ^ (l16 & 7)) << 3)];

    #pragma unroll
    for (int db = 0; db < 8; ++db) {
      int d = db * 16 + l16;
      #pragma unroll
      for (int ks2 = 0; ks2 < 2; ++ks2) {
        int dc = (ks2 * 4 + quad) ^ (d & 7);
        bf16x8 vb = *(const bf16x8*)&Vs[cur][(d * 8 + dc) * 8];
        o[db] = __builtin_amdgcn_mfma_f32_16x16x32_bf16(pa[ks2], vb, o[db], 0, 0, 0);
      }
    }
  }

  #pragma unroll
  for (int r = 0; r < 4; ++r) {
    float lr = __shfl(lrow, quad * 4 + r, 16);
    float inv = 1.0f / lr;
    size_t row = rowbase + qw0 + quad * 4 + r;
    #pragma unroll
    for (int db = 0; db < 8; ++db)
      outb[row * EMBED + hq + db * 16 + l16] = f2bf(o[db][r] * inv);
  }
}

extern "C" void kernel_launch(void* const* d_in, const int* in_sizes, int n_in,
                              void* d_out, int out_size, void* d_ws, size_t ws_size,
                              hipStream_t stream) {
  const float* x    = (const float*)d_in[0];
  const float* Wqkv = (const float*)d_in[1];
  const float* bqkv = (const float*)d_in[2];
  const float* Wout = (const float*)d_in[3];
  const float* bout = (const float*)d_in[4];
  float* out = (float*)d_out;

  unsigned short* xb    = (unsigned short*)d_ws;
  unsigned short* wqkvT = xb    + (size_t)ROWS * EMBED;    // [6144][2048]
  unsigned short* woutT = wqkvT + (size_t)EMBED * QKVC;    // [2048][2048]
  unsigned short* qkb   = woutT + (size_t)EMBED * EMBED;   // [4096][4096] Q|K
  unsigned short* vtb   = qkb   + (size_t)ROWS * 4096;     // [32*128][2048] V^T
  unsigned short* attnb = vtb   + (size_t)32 * HDIM * SEQ; // [4096][2048]

  // fused prep: cast + both weight transposes (one launch instead of three)
  prep_kernel<<<dim3(24576), 256, 0, stream>>>(x, Wqkv, Wout, xb, wqkvT, woutT);

  // Q|K part: 256x256 8-phase kernel, grid 16x16 = 256 blocks = exactly 1 round
  gemm256_kernel<<<dim3((2 * EMBED / 256) * (ROWS / 256)), 512, 0, stream>>>(
      xb, wqkvT, bqkv, qkb, vtb, ROWS, 2 * EMBED, EMBED);

  // V part: proven 128x128 kernel, MODE 2 (BT/bias pre-offset to the V third)
  gemm_kernel<2><<<dim3(EMBED / 128, ROWS / 128), 256, 0, stream>>>(
      xb, wqkvT + (size_t)(2 * EMBED) * EMBED, bqkv + 2 * EMBED,
      nullptr, vtb, nullptr, ROWS, EMBED, EMBED);

  // attention: 512 blocks = 2 blocks/CU (80KB LDS each)
  attn_kernel<<<dim3(32, 16), 512, 0, stream>>>(qkb, vtb, attnb);

  gemm_kernel<1><<<dim3(EMBED / 128, ROWS / 128), 256, 0, stream>>>(
      attnb, woutT, bout, nullptr, nullptr, out, ROWS, EMBED, EMBED);
}

// Round 7
// 368.441 us; speedup vs baseline: 1.0249x; 1.0249x over previous
//
#include <hip/hip_runtime.h>
#include <hip/hip_bf16.h>

#define EMBED  2048
#define SEQ    2048
#define BATCH  2
#define NHEADS 16
#define HDIM   128
#define QKVC   (3*EMBED)    // 6144
#define ROWS   (BATCH*SEQ)  // 4096

typedef __attribute__((ext_vector_type(8))) short bf16x8;
typedef __attribute__((ext_vector_type(4))) float f32x4;
typedef __attribute__((ext_vector_type(16))) float f32x16;

typedef const __attribute__((address_space(1))) void* gptr1_t;
typedef __attribute__((address_space(3))) void* lptr3_t;

__device__ __forceinline__ void gld16(const unsigned short* g, unsigned short* l) {
  __builtin_amdgcn_global_load_lds((gptr1_t)g, (lptr3_t)l, 16, 0, 0);
}

__device__ __forceinline__ unsigned short f2bf(float f) {
  unsigned int x = __float_as_uint(f);
  unsigned int r = (x + 0x7fffu + ((x >> 16) & 1u)) >> 16;
  return (unsigned short)r;
}

// ---------------- fused prep: cast x -> bf16 AND both W transposes ----------------
__global__ __launch_bounds__(256)
void prep_kernel(const float* __restrict__ x,
                 const float* __restrict__ Wqkv,
                 const float* __restrict__ Wout,
                 unsigned short* __restrict__ xb,
                 unsigned short* __restrict__ wqkvT,
                 unsigned short* __restrict__ woutT) {
  __shared__ float tile[32][33];
  const int bid = blockIdx.x;
  if (bid < 8192) {
    int i = bid * 256 + threadIdx.x;
    float4 v = reinterpret_cast<const float4*>(x)[i];
    ushort4 o;
    o.x = f2bf(v.x); o.y = f2bf(v.y); o.z = f2bf(v.z); o.w = f2bf(v.w);
    reinterpret_cast<ushort4*>(xb)[i] = o;
    return;
  }
  const float* in; unsigned short* out; int C, bx, by;
  if (bid < 8192 + 12288) {
    int j = bid - 8192;  bx = j % 192; by = j / 192;  in = Wqkv; out = wqkvT; C = QKVC;
  } else {
    int j = bid - 20480; bx = j % 64;  by = j / 64;   in = Wout; out = woutT; C = EMBED;
  }
  const int R = EMBED;
  int tx = threadIdx.x & 31, ty = threadIdx.x >> 5;   // 32 x 8
  int c0 = bx * 32, r0 = by * 32;
  #pragma unroll
  for (int i = 0; i < 32; i += 8)
    tile[ty + i][tx] = in[(size_t)(r0 + ty + i) * C + c0 + tx];
  __syncthreads();
  #pragma unroll
  for (int i = 0; i < 32; i += 8)
    out[(size_t)(c0 + ty + i) * R + r0 + tx] = f2bf(tile[tx][ty + i]);
}

// ---------------- 128x128 MFMA GEMM ----------
// MODE 1: f32 out, row stride N (out-projection)
// MODE 2: V-only QKV third: BT/bias pre-offset by 4096; output transposed into vt
template<int MODE>
__global__ __launch_bounds__(256)
void gemm_kernel(const unsigned short* __restrict__ A,
                 const unsigned short* __restrict__ BT,
                 const float* __restrict__ bias,
                 unsigned short* __restrict__ outb,
                 unsigned short* __restrict__ vt,
                 float* __restrict__ outf,
                 int M, int N, int K) {
  __shared__ unsigned short As[2 * 128 * 32];   // two BK=32 sub-tiles
  __shared__ unsigned short Bs[2 * 128 * 32];
  const int t = threadIdx.x;
  const int lane = t & 63, wave = t >> 6;
  const int l31 = lane & 31, hl = lane >> 5;
  const int wm = wave >> 1, wn = wave & 1;
  const int m0 = blockIdx.y * 128, n0 = blockIdx.x * 128;

  f32x16 acc[2][2] = {};

  int aoff[2][4], boff[2][4];
  #pragma unroll
  for (int i = 0; i < 2; ++i) {
    int m = wm * 64 + i * 32 + l31;
    int pm = ((m >> 2) ^ m) & 3;
    int n = wn * 64 + i * 32 + l31;
    int pn = ((n >> 2) ^ n) & 3;
    #pragma unroll
    for (int s4 = 0; s4 < 4; ++s4) {
      int st = s4 >> 1, c = (s4 & 1) * 2 + hl;
      aoff[i][s4] = st * 4096 + (m * 4 + (c ^ pm)) * 8;
      boff[i][s4] = st * 4096 + (n * 4 + (c ^ pn)) * 8;
    }
  }
  int ldso[4];
  const unsigned short* Ag[4];
  const unsigned short* Bg[4];
  #pragma unroll
  for (int i = 0; i < 4; ++i) {
    int cc = i * 256 + t;
    int st = cc >> 9, w = cc & 511;
    int r = w >> 2, s = w & 3;
    int d = s ^ (((r >> 2) ^ r) & 3);
    ldso[i] = st * 4096 + w * 8;
    Ag[i] = A  + (size_t)(m0 + r) * K + st * 32 + d * 8;
    Bg[i] = BT + (size_t)(n0 + r) * K + st * 32 + d * 8;
  }

  for (int k0 = 0; k0 < K; k0 += 64) {
    #pragma unroll
    for (int i = 0; i < 4; ++i) gld16(Ag[i] + k0, &As[ldso[i]]);
    #pragma unroll
    for (int i = 0; i < 4; ++i) gld16(Bg[i] + k0, &Bs[ldso[i]]);
    __syncthreads();
    #pragma unroll
    for (int s4 = 0; s4 < 4; ++s4) {
      bf16x8 a0 = *(const bf16x8*)&As[aoff[0][s4]];
      bf16x8 a1 = *(const bf16x8*)&As[aoff[1][s4]];
      bf16x8 b0 = *(const bf16x8*)&Bs[boff[0][s4]];
      bf16x8 b1 = *(const bf16x8*)&Bs[boff[1][s4]];
      acc[0][0] = __builtin_amdgcn_mfma_f32_32x32x16_bf16(a0, b0, acc[0][0], 0, 0, 0);
      acc[0][1] = __builtin_amdgcn_mfma_f32_32x32x16_bf16(a0, b1, acc[0][1], 0, 0, 0);
      acc[1][0] = __builtin_amdgcn_mfma_f32_32x32x16_bf16(a1, b0, acc[1][0], 0, 0, 0);
      acc[1][1] = __builtin_amdgcn_mfma_f32_32x32x16_bf16(a1, b1, acc[1][1], 0, 0, 0);
    }
    __syncthreads();
  }

  #pragma unroll
  for (int i = 0; i < 2; ++i) {
    int rowb = m0 + wm * 64 + i * 32 + 4 * hl;
    #pragma unroll
    for (int j = 0; j < 2; ++j) {
      int col = n0 + wn * 64 + j * 32 + l31;
      float bv = bias[col];
      if (MODE == 1) {
        #pragma unroll
        for (int g = 0; g < 4; ++g)
          #pragma unroll
          for (int rr = 0; rr < 4; ++rr)
            outf[(size_t)(rowb + 8 * g + rr) * N + col] = acc[i][j][4 * g + rr] + bv;
      } else {
        // MODE 2: V region (BT/bias pre-offset): write transposed into vt
        int hd = col;
        int b = rowb >> 11;
        int sbase = rowb & 2047;
        #pragma unroll
        for (int g = 0; g < 4; ++g) {
          ushort4 w;
          w.x = f2bf(acc[i][j][4 * g + 0] + bv);
          w.y = f2bf(acc[i][j][4 * g + 1] + bv);
          w.z = f2bf(acc[i][j][4 * g + 2] + bv);
          w.w = f2bf(acc[i][j][4 * g + 3] + bv);
          *(ushort4*)&vt[(((size_t)(b << 11) + hd) << 11) + sbase + 8 * g] = w;
        }
      }
    }
  }
}

// ---------------- 256x256 8-phase MFMA GEMM (Q|K part) ------
#define FENCE256 asm volatile("" ::: "memory")
#define BAR256 do { FENCE256; __builtin_amdgcn_s_barrier(); FENCE256; } while (0)

#define STAGE_A256(BUF, H, KT) do { if ((KT) < NT) { \
    gld16(Asrc[0] + (H)*128*K + (KT)*64, &As[BUF][(H)*8192 + sdst0]); \
    gld16(Asrc[1] + (H)*128*K + (KT)*64, &As[BUF][(H)*8192 + sdst1]); } } while (0)
#define STAGE_B256(BUF, H, KT) do { if ((KT) < NT) { \
    gld16(Bsrc[0] + (H)*128*K + (KT)*64, &Bs[BUF][(H)*8192 + sdst0]); \
    gld16(Bsrc[1] + (H)*128*K + (KT)*64, &Bs[BUF][(H)*8192 + sdst1]); } } while (0)

#define READ_A256(BUF, MH) do { _Pragma("unroll") \
  for (int mf = 0; mf < 4; ++mf) { \
    av[mf][0] = *(const bf16x8*)&As[BUF][arow0 + (MH)*4096 + mf*1024 + ck0]; \
    av[mf][1] = *(const bf16x8*)&As[BUF][arow0 + (MH)*4096 + mf*1024 + ck1]; } } while (0)
#define READ_B256(BUF, NH, DST) do { _Pragma("unroll") \
  for (int nf = 0; nf < 2; ++nf) { \
    DST[nf][0] = *(const bf16x8*)&Bs[BUF][brow0 + (NH)*2048 + nf*1024 + ck0]; \
    DST[nf][1] = *(const bf16x8*)&Bs[BUF][brow0 + (NH)*2048 + nf*1024 + ck1]; } } while (0)

#define MFMA_Q256(MH, NH, B_) do { \
  __builtin_amdgcn_s_setprio(1); \
  _Pragma("unroll") \
  for (int mf = 0; mf < 4; ++mf) { \
    _Pragma("unroll") \
    for (int nf = 0; nf < 2; ++nf) { \
      f32x4 c = acc[(MH)*4 + mf][(NH)*2 + nf]; \
      c = __builtin_amdgcn_mfma_f32_16x16x32_bf16(av[mf][0], B_[nf][0], c, 0, 0, 0); \
      c = __builtin_amdgcn_mfma_f32_16x16x32_bf16(av[mf][1], B_[nf][1], c, 0, 0, 0); \
      acc[(MH)*4 + mf][(NH)*2 + nf] = c; } } \
  __builtin_amdgcn_s_setprio(0); } while (0)

#define VMCNT256(LAST) do { \
  if (LAST) asm volatile("s_waitcnt vmcnt(0)" ::: "memory"); \
  else      asm volatile("s_waitcnt vmcnt(4)" ::: "memory"); } while (0)

__global__ __launch_bounds__(512, 2)
void gemm256_kernel(const unsigned short* __restrict__ A,
                    const unsigned short* __restrict__ BT,
                    const float* __restrict__ bias,
                    unsigned short* __restrict__ outb,
                    unsigned short* __restrict__ vt,
                    int M, int N, int K) {
  __shared__ __align__(16) unsigned short As[2][16384];
  __shared__ __align__(16) unsigned short Bs[2][16384];
  const int t = threadIdx.x;
  const int lane = t & 63, wave = t >> 6;
  const int l16 = lane & 15, quad = (lane >> 4) & 3;
  const int wm = wave >> 2, wn = wave & 3;

  const int nwg = (int)gridDim.x;
  int swz = (int)blockIdx.x;
  if ((nwg & 7) == 0) swz = (swz & 7) * (nwg >> 3) + (swz >> 3);
  const int ntiles = N >> 8;
  const int mt = swz / ntiles, nt = swz % ntiles;
  const int m0 = mt << 8, n0 = nt << 8;

  const int NT = K >> 6;   // K-tiles of 64 (32)
  const int NI = NT >> 1;  // 8-phase iterations (16)

  f32x4 acc[8][4] = {};
  bf16x8 av[4][2], bv0[2][2], bv1[2][2];

  const unsigned short* Asrc[2];
  const unsigned short* Bsrc[2];
  int sdst0, sdst1;
  {
    int cc0 = t, cc1 = 512 + t;
    int r0 = cc0 >> 3, c0 = cc0 & 7;
    int r1 = cc1 >> 3, c1 = cc1 & 7;
    Asrc[0] = A  + (size_t)(m0 + r0) * K + ((c0 ^ (r0 & 7)) << 3);
    Asrc[1] = A  + (size_t)(m0 + r1) * K + ((c1 ^ (r1 & 7)) << 3);
    Bsrc[0] = BT + (size_t)(n0 + r0) * K + ((c0 ^ (r0 & 7)) << 3);
    Bsrc[1] = BT + (size_t)(n0 + r1) * K + ((c1 ^ (r1 & 7)) << 3);
    sdst0 = cc0 << 3;
    sdst1 = cc1 << 3;
  }

  const int ck0 = ((quad) ^ (l16 & 7)) << 3;       // k-sub 0 chunk
  const int ck1 = ((4 + quad) ^ (l16 & 7)) << 3;   // k-sub 1 chunk
  const int arow0 = (wm * 128 + l16) * 64;
  const int brow0 = (wn * 64 + l16) * 64;

  STAGE_A256(0, 0, 0); STAGE_A256(0, 1, 0);
  STAGE_B256(0, 0, 0); STAGE_B256(0, 1, 0);
  STAGE_B256(1, 0, 1); STAGE_B256(1, 1, 1);
  asm volatile("s_waitcnt vmcnt(4)" ::: "memory");
  BAR256;

  for (int it = 0; it < NI; ++it) {
    const int kt1 = 2 * it + 1, ktA = 2 * it + 2, ktB = 2 * it + 3;
    const bool last = (it == NI - 1);

    READ_A256(0, 0); READ_B256(0, 0, bv0);
    STAGE_A256(1, 0, kt1);
    BAR256; MFMA_Q256(0, 0, bv0); BAR256;
    READ_B256(0, 1, bv1);
    STAGE_A256(1, 1, kt1);
    BAR256; MFMA_Q256(0, 1, bv1); BAR256;
    READ_A256(0, 1);
    STAGE_B256(0, 0, ktA);
    BAR256; MFMA_Q256(1, 1, bv1); BAR256;
    STAGE_B256(0, 1, ktA);
    BAR256; MFMA_Q256(1, 0, bv0);
    VMCNT256(last);
    BAR256;
    READ_A256(1, 0); READ_B256(1, 0, bv0);
    STAGE_A256(0, 0, ktA);
    BAR256; MFMA_Q256(0, 0, bv0); BAR256;
    READ_B256(1, 1, bv1);
    STAGE_A256(0, 1, ktA);
    BAR256; MFMA_Q256(0, 1, bv1); BAR256;
    READ_A256(1, 1);
    STAGE_B256(1, 0, ktB);
    BAR256; MFMA_Q256(1, 1, bv1); BAR256;
    STAGE_B256(1, 1, ktB);
    BAR256; MFMA_Q256(1, 0, bv0);
    VMCNT256(last);
    BAR256;
  }

  // epilogue; Q region pre-scaled by 1/sqrt(128)*log2(e)
  const float scl = (n0 < EMBED) ? (0.08838834764831845f * 1.4426950408889634f) : 1.0f;
  #pragma unroll
  for (int mf = 0; mf < 8; ++mf) {
    const int row = m0 + wm * 128 + (mf >> 2) * 64 + (mf & 3) * 16 + quad * 4;
    #pragma unroll
    for (int nf = 0; nf < 4; ++nf) {
      const int col = n0 + wn * 64 + (nf >> 1) * 32 + (nf & 1) * 16 + l16;
      const float bv = bias[col];
      #pragma unroll
      for (int r = 0; r < 4; ++r)
        outb[(size_t)(row + r) * 4096 + col] = f2bf((acc[mf][nf][r] + bv) * scl);
    }
  }
  (void)vt; (void)M;
}

// ---------------- flash attention (S^T form, double-buffered K/V) ----------------
// Round-7: true 2 blocks/CU. Ps halved to [8][16*32] (P staged one 32-kv half at
// a time; PV's ks2 split consumes exactly one half per pass). LDS = 32K+32K+8K =
// 73728 B -> 2 x 73728 = 147456 <= 163840 with 16 KB headroom -> 2 blocks/CU.
// Plain __launch_bounds__(512): no VGPR clamp (r6's ",4" forced 64 VGPR -> spills).
// Grid (32,16): qt(y) = y<8 ? 15-y : y-8 -> co-resident pairs sum to constant work.
__global__ __launch_bounds__(512)
void attn_kernel(const unsigned short* __restrict__ qk,   // [4096][4096] Q|K bf16
                 const unsigned short* __restrict__ vt,   // [32*128][2048] V^T bf16
                 unsigned short* __restrict__ outb) {     // [4096][2048] bf16
  __shared__ unsigned short Ks[2][64 * 128];
  __shared__ unsigned short Vs[2][64 * 128];
  __shared__ unsigned short Ps[8][16 * 32];
  const int t = threadIdx.x;
  const int lane = t & 63, wave = t >> 6;
  const int quad = lane >> 4, l16 = lane & 15;
  const int bh = blockIdx.x;
  const int y = blockIdx.y;
  const int qt = (y < 8) ? (15 - y) : (y - 8);    // balanced co-residency mapping
  const int b = bh >> 4, h = bh & 15;
  const size_t rowbase = (size_t)b * SEQ;
  const int hq = h * HDIM;
  const unsigned short* vbase = vt + ((size_t)bh * HDIM) * SEQ;

  const int qw0 = qt * 128 + wave * 16;
  const int jmax = 2 * qt + 1;                    // KV tiles of 64: 0..jmax

  bf16x8 qf[4];
  {
    const unsigned short* qrow = qk + (size_t)(rowbase + qw0 + l16) * 4096 + hq + quad * 8;
    #pragma unroll
    for (int s = 0; s < 4; ++s) qf[s] = *(const bf16x8*)(qrow + s * 32);
  }

  f32x4 o[8] = {};
  float mrow = -1e30f, lrow = 0.f;

  // prologue: stage tile 0 into buffer 0 (1024 chunks over 512 threads)
  #pragma unroll
  for (int i = 0; i < 2; ++i) {
    int cc = i * 512 + t;
    int kv = cc >> 4, sc = cc & 15;
    int dc = sc ^ (kv & 15);
    gld16(qk + (size_t)(rowbase + kv) * 4096 + EMBED + hq + dc * 8, &Ks[0][cc * 8]);
  }
  #pragma unroll
  for (int i = 0; i < 2; ++i) {
    int cc = i * 512 + t;
    int d = cc >> 3, c = cc & 7;
    int dc = c ^ (d & 7);
    gld16(vbase + (size_t)d * SEQ + dc * 8, &Vs[0][cc * 8]);
  }

  for (int j = 0; j <= jmax; ++j) {
    const int cur = j & 1;
    __syncthreads();   // buf[cur] ready; all reads of buf[cur^1] complete

    if (j < jmax) {    // prefetch tile j+1, overlapped with compute below
      const int kv1 = (j + 1) * 64;
      #pragma unroll
      for (int i = 0; i < 2; ++i) {
        int cc = i * 512 + t;
        int kv = cc >> 4, sc = cc & 15;
        int dc = sc ^ (kv & 15);
        gld16(qk + (size_t)(rowbase + kv1 + kv) * 4096 + EMBED + hq + dc * 8, &Ks[cur ^ 1][cc * 8]);
      }
      #pragma unroll
      for (int i = 0; i < 2; ++i) {
        int cc = i * 512 + t;
        int d = cc >> 3, c = cc & 7;
        int dc = c ^ (d & 7);
        gld16(vbase + (size_t)d * SEQ + kv1 + dc * 8, &Vs[cur ^ 1][cc * 8]);
      }
    }

    const int kv0 = j * 64;
    if (kv0 > qw0 + 15) continue;   // wave-uniform: tile fully masked for this wave
                                    // (no barriers below -> safe divergence)

    f32x4 sacc[4] = {};
    #pragma unroll
    for (int nb = 0; nb < 4; ++nb) {
      int kvr = nb * 16 + l16;
      #pragma unroll
      for (int ks = 0; ks < 4; ++ks) {
        int dc2 = (ks * 4 + quad) ^ (kvr & 15);
        bf16x8 kb = *(const bf16x8*)&Ks[cur][(kvr * 16 + dc2) * 8];
        sacc[nb] = __builtin_amdgcn_mfma_f32_16x16x32_bf16(kb, qf[ks], sacc[nb], 0, 0, 0);
      }
    }

    float p[4][4];
    float smax = -1e30f;
    if (kv0 + 63 > qw0) {           // diagonal region for this wave: apply causal mask
      const int qg = qw0 + l16;
      #pragma unroll
      for (int nb = 0; nb < 4; ++nb)
        #pragma unroll
        for (int r = 0; r < 4; ++r) {
          float v = sacc[nb][r];
          if ((kv0 + nb * 16 + quad * 4 + r) > qg) v = -1e30f;
          p[nb][r] = v;
          smax = fmaxf(smax, v);
        }
    } else {
      #pragma unroll
      for (int nb = 0; nb < 4; ++nb)
        #pragma unroll
        for (int r = 0; r < 4; ++r) {
          float v = sacc[nb][r];
          p[nb][r] = v;
          smax = fmaxf(smax, v);
        }
    }
    smax = fmaxf(smax, __shfl_xor(smax, 16));
    smax = fmaxf(smax, __shfl_xor(smax, 32));

    const float mold = mrow;
    const unsigned long long grew = __ballot(smax > mold);
    const float mnew = fmaxf(mold, smax);
    mrow = mnew;

    float rs = 0.f;
    #pragma unroll
    for (int nb = 0; nb < 4; ++nb)
      #pragma unroll
      for (int r = 0; r < 4; ++r) {
        float pv = exp2f(p[nb][r] - mnew);
        p[nb][r] = pv;
        rs += pv;
      }
    rs += __shfl_xor(rs, 16);
    rs += __shfl_xor(rs, 32);

    if (grew) {   // wave-uniform: some q-row's max increased -> rescale O and lrow
      float alpha = exp2f(mold - mnew);   // ==1 for rows that didn't grow
      lrow = lrow * alpha + rs;
      #pragma unroll
      for (int r = 0; r < 4; ++r) {
        float av = __shfl(alpha, quad * 4 + r, 16);
        #pragma unroll
        for (int db = 0; db < 8; ++db) o[db][r] *= av;
      }
    } else {
      lrow += rs;
    }

    // PV in two 32-kv halves through an 8KB Ps buffer (per-wave, in-order DS pipe:
    // half h's pa read precedes half h+1's overwrite in program order).
    unsigned short* pw = &Ps[wave][0];
    #pragma unroll
    for (int hh = 0; hh < 2; ++hh) {
      #pragma unroll
      for (int nn = 0; nn < 2; ++nn) {
        int nb = hh * 2 + nn;
        __hip_bfloat162 lo = __float22bfloat162_rn(make_float2(p[nb][0], p[nb][1]));
        __hip_bfloat162 hi = __float22bfloat162_rn(make_float2(p[nb][2], p[nb][3]));
        ushort4 w;
        w.x = *(unsigned short*)&lo.x; w.y = *(unsigned short*)&lo.y;
        w.z = *(unsigned short*)&hi.x; w.w = *(unsigned short*)&hi.y;
        // logical slot (16B) = nn*2 + (quad>>1); 4-slot XOR swizzle with l16&3
        *(ushort4*)&pw[l16 * 32 + (((nn * 2 + (quad >> 1)) ^ (l16 & 3)) << 3) + (quad & 1) * 4] = w;
      }
      asm volatile("s_waitcnt lgkmcnt(0)" ::: "memory");
      bf16x8 pa = *(const bf16x8*)&pw[l16 * 32 + ((quad ^ (l16 & 3)) << 3)];

      #pragma unroll
      for (int db = 0; db < 8; ++db) {
        int d = db * 16 + l16;
        int dc = (hh * 4 + quad) ^ (d & 7);
        bf16x8 vb = *(const bf16x8*)&Vs[cur][(d * 8 + dc) * 8];
        o[db] = __builtin_amdgcn_mfma_f32_16x16x32_bf16(pa, vb, o[db], 0, 0, 0);
      }
    }
  }

  #pragma unroll
  for (int r = 0; r < 4; ++r) {
    float lr = __shfl(lrow, quad * 4 + r, 16);
    float inv = 1.0f / lr;
    size_t row = rowbase + qw0 + quad * 4 + r;
    #pragma unroll
    for (int db = 0; db < 8; ++db)
      outb[row * EMBED + hq + db * 16 + l16] = f2bf(o[db][r] * inv);
  }
}

extern "C" void kernel_launch(void* const* d_in, const int* in_sizes, int n_in,
                              void* d_out, int out_size, void* d_ws, size_t ws_size,
                              hipStream_t stream) {
  const float* x    = (const float*)d_in[0];
  const float* Wqkv = (const float*)d_in[1];
  const float* bqkv = (const float*)d_in[2];
  const float* Wout = (const float*)d_in[3];
  const float* bout = (const float*)d_in[4];
  float* out = (float*)d_out;

  unsigned short* xb    = (unsigned short*)d_ws;
  unsigned short* wqkvT = xb    + (size_t)ROWS * EMBED;    // [6144][2048]
  unsigned short* woutT = wqkvT + (size_t)EMBED * QKVC;    // [2048][2048]
  unsigned short* qkb   = woutT + (size_t)EMBED * EMBED;   // [4096][4096] Q|K
  unsigned short* vtb   = qkb   + (size_t)ROWS * 4096;     // [32*128][2048] V^T
  unsigned short* attnb = vtb   + (size_t)32 * HDIM * SEQ; // [4096][2048]

  // fused prep: cast + both weight transposes (one launch instead of three)
  prep_kernel<<<dim3(24576), 256, 0, stream>>>(x, Wqkv, Wout, xb, wqkvT, woutT);

  // Q|K part: 256x256 8-phase kernel, grid 16x16 = 256 blocks = exactly 1 round
  gemm256_kernel<<<dim3((2 * EMBED / 256) * (ROWS / 256)), 512, 0, stream>>>(
      xb, wqkvT, bqkv, qkb, vtb, ROWS, 2 * EMBED, EMBED);

  // V part: proven 128x128 kernel, MODE 2 (BT/bias pre-offset to the V third)
  gemm_kernel<2><<<dim3(EMBED / 128, ROWS / 128), 256, 0, stream>>>(
      xb, wqkvT + (size_t)(2 * EMBED) * EMBED, bqkv + 2 * EMBED,
      nullptr, vtb, nullptr, ROWS, EMBED, EMBED);

  // attention: 512 blocks, 72KB LDS each -> 2 blocks/CU
  attn_kernel<<<dim3(32, 16), 512, 0, stream>>>(qkb, vtb, attnb);

  gemm_kernel<1><<<dim3(EMBED / 128, ROWS / 128), 256, 0, stream>>>(
      attnb, woutT, bout, nullptr, nullptr, out, ROWS, EMBED, EMBED);
}

// Round 8
// 360.566 us; speedup vs baseline: 1.0473x; 1.0218x over previous
//
#include <hip/hip_runtime.h>
#include <hip/hip_bf16.h>

#define EMBED  2048
#define SEQ    2048
#define BATCH  2
#define NHEADS 16
#define HDIM   128
#define QKVC   (3*EMBED)    // 6144
#define ROWS   (BATCH*SEQ)  // 4096

typedef __attribute__((ext_vector_type(8))) short bf16x8;
typedef __attribute__((ext_vector_type(4))) float f32x4;
typedef __attribute__((ext_vector_type(16))) float f32x16;

typedef const __attribute__((address_space(1))) void* gptr1_t;
typedef __attribute__((address_space(3))) void* lptr3_t;

__device__ __forceinline__ void gld16(const unsigned short* g, unsigned short* l) {
  __builtin_amdgcn_global_load_lds((gptr1_t)g, (lptr3_t)l, 16, 0, 0);
}

__device__ __forceinline__ unsigned short f2bf(float f) {
  unsigned int x = __float_as_uint(f);
  unsigned int r = (x + 0x7fffu + ((x >> 16) & 1u)) >> 16;
  return (unsigned short)r;
}

// ---------------- fused prep: cast x -> bf16 AND both W transposes ----------------
__global__ __launch_bounds__(256)
void prep_kernel(const float* __restrict__ x,
                 const float* __restrict__ Wqkv,
                 const float* __restrict__ Wout,
                 unsigned short* __restrict__ xb,
                 unsigned short* __restrict__ wqkvT,
                 unsigned short* __restrict__ woutT) {
  __shared__ float tile[32][33];
  const int bid = blockIdx.x;
  if (bid < 8192) {
    int i = bid * 256 + threadIdx.x;
    float4 v = reinterpret_cast<const float4*>(x)[i];
    ushort4 o;
    o.x = f2bf(v.x); o.y = f2bf(v.y); o.z = f2bf(v.z); o.w = f2bf(v.w);
    reinterpret_cast<ushort4*>(xb)[i] = o;
    return;
  }
  const float* in; unsigned short* out; int C, bx, by;
  if (bid < 8192 + 12288) {
    int j = bid - 8192;  bx = j % 192; by = j / 192;  in = Wqkv; out = wqkvT; C = QKVC;
  } else {
    int j = bid - 20480; bx = j % 64;  by = j / 64;   in = Wout; out = woutT; C = EMBED;
  }
  const int R = EMBED;
  int tx = threadIdx.x & 31, ty = threadIdx.x >> 5;   // 32 x 8
  int c0 = bx * 32, r0 = by * 32;
  #pragma unroll
  for (int i = 0; i < 32; i += 8)
    tile[ty + i][tx] = in[(size_t)(r0 + ty + i) * C + c0 + tx];
  __syncthreads();
  #pragma unroll
  for (int i = 0; i < 32; i += 8)
    out[(size_t)(c0 + ty + i) * R + r0 + tx] = f2bf(tile[tx][ty + i]);
}

// ---------------- 128x128 MFMA GEMM ----------
// MODE 1: f32 out, row stride N (out-projection)
// MODE 2: V-only QKV third: BT/bias pre-offset by 4096; output transposed into vt
template<int MODE>
__global__ __launch_bounds__(256)
void gemm_kernel(const unsigned short* __restrict__ A,
                 const unsigned short* __restrict__ BT,
                 const float* __restrict__ bias,
                 unsigned short* __restrict__ outb,
                 unsigned short* __restrict__ vt,
                 float* __restrict__ outf,
                 int M, int N, int K) {
  __shared__ unsigned short As[2 * 128 * 32];   // two BK=32 sub-tiles
  __shared__ unsigned short Bs[2 * 128 * 32];
  const int t = threadIdx.x;
  const int lane = t & 63, wave = t >> 6;
  const int l31 = lane & 31, hl = lane >> 5;
  const int wm = wave >> 1, wn = wave & 1;
  const int m0 = blockIdx.y * 128, n0 = blockIdx.x * 128;

  f32x16 acc[2][2] = {};

  int aoff[2][4], boff[2][4];
  #pragma unroll
  for (int i = 0; i < 2; ++i) {
    int m = wm * 64 + i * 32 + l31;
    int pm = ((m >> 2) ^ m) & 3;
    int n = wn * 64 + i * 32 + l31;
    int pn = ((n >> 2) ^ n) & 3;
    #pragma unroll
    for (int s4 = 0; s4 < 4; ++s4) {
      int st = s4 >> 1, c = (s4 & 1) * 2 + hl;
      aoff[i][s4] = st * 4096 + (m * 4 + (c ^ pm)) * 8;
      boff[i][s4] = st * 4096 + (n * 4 + (c ^ pn)) * 8;
    }
  }
  int ldso[4];
  const unsigned short* Ag[4];
  const unsigned short* Bg[4];
  #pragma unroll
  for (int i = 0; i < 4; ++i) {
    int cc = i * 256 + t;
    int st = cc >> 9, w = cc & 511;
    int r = w >> 2, s = w & 3;
    int d = s ^ (((r >> 2) ^ r) & 3);
    ldso[i] = st * 4096 + w * 8;
    Ag[i] = A  + (size_t)(m0 + r) * K + st * 32 + d * 8;
    Bg[i] = BT + (size_t)(n0 + r) * K + st * 32 + d * 8;
  }

  for (int k0 = 0; k0 < K; k0 += 64) {
    #pragma unroll
    for (int i = 0; i < 4; ++i) gld16(Ag[i] + k0, &As[ldso[i]]);
    #pragma unroll
    for (int i = 0; i < 4; ++i) gld16(Bg[i] + k0, &Bs[ldso[i]]);
    __syncthreads();
    #pragma unroll
    for (int s4 = 0; s4 < 4; ++s4) {
      bf16x8 a0 = *(const bf16x8*)&As[aoff[0][s4]];
      bf16x8 a1 = *(const bf16x8*)&As[aoff[1][s4]];
      bf16x8 b0 = *(const bf16x8*)&Bs[boff[0][s4]];
      bf16x8 b1 = *(const bf16x8*)&Bs[boff[1][s4]];
      acc[0][0] = __builtin_amdgcn_mfma_f32_32x32x16_bf16(a0, b0, acc[0][0], 0, 0, 0);
      acc[0][1] = __builtin_amdgcn_mfma_f32_32x32x16_bf16(a0, b1, acc[0][1], 0, 0, 0);
      acc[1][0] = __builtin_amdgcn_mfma_f32_32x32x16_bf16(a1, b0, acc[1][0], 0, 0, 0);
      acc[1][1] = __builtin_amdgcn_mfma_f32_32x32x16_bf16(a1, b1, acc[1][1], 0, 0, 0);
    }
    __syncthreads();
  }

  #pragma unroll
  for (int i = 0; i < 2; ++i) {
    int rowb = m0 + wm * 64 + i * 32 + 4 * hl;
    #pragma unroll
    for (int j = 0; j < 2; ++j) {
      int col = n0 + wn * 64 + j * 32 + l31;
      float bv = bias[col];
      if (MODE == 1) {
        #pragma unroll
        for (int g = 0; g < 4; ++g)
          #pragma unroll
          for (int rr = 0; rr < 4; ++rr)
            outf[(size_t)(rowb + 8 * g + rr) * N + col] = acc[i][j][4 * g + rr] + bv;
      } else {
        // MODE 2: V region (BT/bias pre-offset): write transposed into vt
        int hd = col;
        int b = rowb >> 11;
        int sbase = rowb & 2047;
        #pragma unroll
        for (int g = 0; g < 4; ++g) {
          ushort4 w;
          w.x = f2bf(acc[i][j][4 * g + 0] + bv);
          w.y = f2bf(acc[i][j][4 * g + 1] + bv);
          w.z = f2bf(acc[i][j][4 * g + 2] + bv);
          w.w = f2bf(acc[i][j][4 * g + 3] + bv);
          *(ushort4*)&vt[(((size_t)(b << 11) + hd) << 11) + sbase + 8 * g] = w;
        }
      }
    }
  }
}

// ---------------- 256x256 8-phase MFMA GEMM (Q|K part) ------
#define FENCE256 asm volatile("" ::: "memory")
#define BAR256 do { FENCE256; __builtin_amdgcn_s_barrier(); FENCE256; } while (0)

#define STAGE_A256(BUF, H, KT) do { if ((KT) < NT) { \
    gld16(Asrc[0] + (H)*128*K + (KT)*64, &As[BUF][(H)*8192 + sdst0]); \
    gld16(Asrc[1] + (H)*128*K + (KT)*64, &As[BUF][(H)*8192 + sdst1]); } } while (0)
#define STAGE_B256(BUF, H, KT) do { if ((KT) < NT) { \
    gld16(Bsrc[0] + (H)*128*K + (KT)*64, &Bs[BUF][(H)*8192 + sdst0]); \
    gld16(Bsrc[1] + (H)*128*K + (KT)*64, &Bs[BUF][(H)*8192 + sdst1]); } } while (0)

#define READ_A256(BUF, MH) do { _Pragma("unroll") \
  for (int mf = 0; mf < 4; ++mf) { \
    av[mf][0] = *(const bf16x8*)&As[BUF][arow0 + (MH)*4096 + mf*1024 + ck0]; \
    av[mf][1] = *(const bf16x8*)&As[BUF][arow0 + (MH)*4096 + mf*1024 + ck1]; } } while (0)
#define READ_B256(BUF, NH, DST) do { _Pragma("unroll") \
  for (int nf = 0; nf < 2; ++nf) { \
    DST[nf][0] = *(const bf16x8*)&Bs[BUF][brow0 + (NH)*2048 + nf*1024 + ck0]; \
    DST[nf][1] = *(const bf16x8*)&Bs[BUF][brow0 + (NH)*2048 + nf*1024 + ck1]; } } while (0)

#define MFMA_Q256(MH, NH, B_) do { \
  __builtin_amdgcn_s_setprio(1); \
  _Pragma("unroll") \
  for (int mf = 0; mf < 4; ++mf) { \
    _Pragma("unroll") \
    for (int nf = 0; nf < 2; ++nf) { \
      f32x4 c = acc[(MH)*4 + mf][(NH)*2 + nf]; \
      c = __builtin_amdgcn_mfma_f32_16x16x32_bf16(av[mf][0], B_[nf][0], c, 0, 0, 0); \
      c = __builtin_amdgcn_mfma_f32_16x16x32_bf16(av[mf][1], B_[nf][1], c, 0, 0, 0); \
      acc[(MH)*4 + mf][(NH)*2 + nf] = c; } } \
  __builtin_amdgcn_s_setprio(0); } while (0)

#define VMCNT256(LAST) do { \
  if (LAST) asm volatile("s_waitcnt vmcnt(0)" ::: "memory"); \
  else      asm volatile("s_waitcnt vmcnt(4)" ::: "memory"); } while (0)

__global__ __launch_bounds__(512, 2)
void gemm256_kernel(const unsigned short* __restrict__ A,
                    const unsigned short* __restrict__ BT,
                    const float* __restrict__ bias,
                    unsigned short* __restrict__ outb,
                    unsigned short* __restrict__ vt,
                    int M, int N, int K) {
  __shared__ __align__(16) unsigned short As[2][16384];
  __shared__ __align__(16) unsigned short Bs[2][16384];
  const int t = threadIdx.x;
  const int lane = t & 63, wave = t >> 6;
  const int l16 = lane & 15, quad = (lane >> 4) & 3;
  const int wm = wave >> 2, wn = wave & 3;

  const int nwg = (int)gridDim.x;
  int swz = (int)blockIdx.x;
  if ((nwg & 7) == 0) swz = (swz & 7) * (nwg >> 3) + (swz >> 3);
  const int ntiles = N >> 8;
  const int mt = swz / ntiles, nt = swz % ntiles;
  const int m0 = mt << 8, n0 = nt << 8;

  const int NT = K >> 6;   // K-tiles of 64 (32)
  const int NI = NT >> 1;  // 8-phase iterations (16)

  f32x4 acc[8][4] = {};
  bf16x8 av[4][2], bv0[2][2], bv1[2][2];

  const unsigned short* Asrc[2];
  const unsigned short* Bsrc[2];
  int sdst0, sdst1;
  {
    int cc0 = t, cc1 = 512 + t;
    int r0 = cc0 >> 3, c0 = cc0 & 7;
    int r1 = cc1 >> 3, c1 = cc1 & 7;
    Asrc[0] = A  + (size_t)(m0 + r0) * K + ((c0 ^ (r0 & 7)) << 3);
    Asrc[1] = A  + (size_t)(m0 + r1) * K + ((c1 ^ (r1 & 7)) << 3);
    Bsrc[0] = BT + (size_t)(n0 + r0) * K + ((c0 ^ (r0 & 7)) << 3);
    Bsrc[1] = BT + (size_t)(n0 + r1) * K + ((c1 ^ (r1 & 7)) << 3);
    sdst0 = cc0 << 3;
    sdst1 = cc1 << 3;
  }

  const int ck0 = ((quad) ^ (l16 & 7)) << 3;       // k-sub 0 chunk
  const int ck1 = ((4 + quad) ^ (l16 & 7)) << 3;   // k-sub 1 chunk
  const int arow0 = (wm * 128 + l16) * 64;
  const int brow0 = (wn * 64 + l16) * 64;

  STAGE_A256(0, 0, 0); STAGE_A256(0, 1, 0);
  STAGE_B256(0, 0, 0); STAGE_B256(0, 1, 0);
  STAGE_B256(1, 0, 1); STAGE_B256(1, 1, 1);
  asm volatile("s_waitcnt vmcnt(4)" ::: "memory");
  BAR256;

  for (int it = 0; it < NI; ++it) {
    const int kt1 = 2 * it + 1, ktA = 2 * it + 2, ktB = 2 * it + 3;
    const bool last = (it == NI - 1);

    READ_A256(0, 0); READ_B256(0, 0, bv0);
    STAGE_A256(1, 0, kt1);
    BAR256; MFMA_Q256(0, 0, bv0); BAR256;
    READ_B256(0, 1, bv1);
    STAGE_A256(1, 1, kt1);
    BAR256; MFMA_Q256(0, 1, bv1); BAR256;
    READ_A256(0, 1);
    STAGE_B256(0, 0, ktA);
    BAR256; MFMA_Q256(1, 1, bv1); BAR256;
    STAGE_B256(0, 1, ktA);
    BAR256; MFMA_Q256(1, 0, bv0);
    VMCNT256(last);
    BAR256;
    READ_A256(1, 0); READ_B256(1, 0, bv0);
    STAGE_A256(0, 0, ktA);
    BAR256; MFMA_Q256(0, 0, bv0); BAR256;
    READ_B256(1, 1, bv1);
    STAGE_A256(0, 1, ktA);
    BAR256; MFMA_Q256(0, 1, bv1); BAR256;
    READ_A256(1, 1);
    STAGE_B256(1, 0, ktB);
    BAR256; MFMA_Q256(1, 1, bv1); BAR256;
    STAGE_B256(1, 1, ktB);
    BAR256; MFMA_Q256(1, 0, bv0);
    VMCNT256(last);
    BAR256;
  }

  // epilogue; Q region pre-scaled by 1/sqrt(128)*log2(e)
  const float scl = (n0 < EMBED) ? (0.08838834764831845f * 1.4426950408889634f) : 1.0f;
  #pragma unroll
  for (int mf = 0; mf < 8; ++mf) {
    const int row = m0 + wm * 128 + (mf >> 2) * 64 + (mf & 3) * 16 + quad * 4;
    #pragma unroll
    for (int nf = 0; nf < 4; ++nf) {
      const int col = n0 + wn * 64 + (nf >> 1) * 32 + (nf & 1) * 16 + l16;
      const float bv = bias[col];
      #pragma unroll
      for (int r = 0; r < 4; ++r)
        outb[(size_t)(row + r) * 4096 + col] = f2bf((acc[mf][nf][r] + bv) * scl);
    }
  }
  (void)vt; (void)M;
}

// ---------------- flash attention (S^T form, T3/T4 counted-vmcnt pipeline) --------
// Round-8: r5-proven structure (grid (32,8), pair-loop, Ps stride-72) with ONLY the
// sync structure changed: triple-buffered K/V, distance-2 prefetch, counted
// s_waitcnt vmcnt(4) + raw s_barrier instead of __syncthreads' vmcnt(0) drain.
// Ledger: at top of iter j, outstanding = G_j (4/thread, iter j-2) + G_{j+1} (4,
// iter j-1); vmcnt(4) drains G_j, keeps G_{j+1} in flight across the barrier.
// G_{j+2} (issued after the barrier) writes buf[(j+2)%3] = buffer of tile j-1,
// whose reads all completed before this barrier. Last iter: vmcnt(0).
// LDS = 48K (Ks[3]) + 48K (Vs[3]) + 18K (Ps) = 114KB -> 1 block/CU (unchanged).
__global__ __launch_bounds__(512)
void attn_kernel(const unsigned short* __restrict__ qk,   // [4096][4096] Q|K bf16
                 const unsigned short* __restrict__ vt,   // [32*128][2048] V^T bf16
                 unsigned short* __restrict__ outb) {     // [4096][2048] bf16
  __shared__ unsigned short Ks[3][64 * 128];
  __shared__ unsigned short Vs[3][64 * 128];
  __shared__ unsigned short Ps[8][16 * 72];
  const int t = threadIdx.x;
  const int lane = t & 63, wave = t >> 6;
  const int quad = lane >> 4, l16 = lane & 15;
  const int bh = blockIdx.x;
  const int pair = blockIdx.y;
  const int b = bh >> 4, h = bh & 15;
  const size_t rowbase = (size_t)b * SEQ;
  const int hq = h * HDIM;
  const unsigned short* vbase = vt + ((size_t)bh * HDIM) * SEQ;

  #pragma unroll
  for (int half = 0; half < 2; ++half) {
    const int qt = half ? (15 - pair) : pair;       // q-tile of 128 rows
    const int qw0 = qt * 128 + wave * 16;
    const int jmax = 2 * qt + 1;                    // KV tiles of 64: 0..jmax (>=1)

    bf16x8 qf[4];
    {
      const unsigned short* qrow = qk + (size_t)(rowbase + qw0 + l16) * 4096 + hq + quad * 8;
      #pragma unroll
      for (int s = 0; s < 4; ++s) qf[s] = *(const bf16x8*)(qrow + s * 32);
    }

    f32x4 o[8] = {};
    float mrow = -1e30f, lrow = 0.f;

    // stage tile kt into buffer bsel (4 gld16 per thread = one vmcnt group)
    auto STAGEKV = [&](int kt, int bsel) {
      const int kvb = kt * 64;
      #pragma unroll
      for (int i = 0; i < 2; ++i) {
        int cc = i * 512 + t;
        int kv = cc >> 4, sc = cc & 15;
        int dc = sc ^ (kv & 15);
        gld16(qk + (size_t)(rowbase + kvb + kv) * 4096 + EMBED + hq + dc * 8, &Ks[bsel][cc * 8]);
      }
      #pragma unroll
      for (int i = 0; i < 2; ++i) {
        int cc = i * 512 + t;
        int d = cc >> 3, c = cc & 7;
        int dc = c ^ (d & 7);
        gld16(vbase + (size_t)d * SEQ + kvb + dc * 8, &Vs[bsel][cc * 8]);
      }
    };

    // prologue: tiles 0,1 in flight (jmax >= 1 always)
    STAGEKV(0, 0);
    STAGEKV(1, 1);

    int cur = 0, nxt2 = 2;   // buffer of tile j; buffer of tile j+2
    for (int j = 0; j <= jmax; ++j) {
      // counted drain: need G_j landed; keep G_{j+1} in flight (if it exists)
      if (j < jmax) { asm volatile("s_waitcnt vmcnt(4)" ::: "memory"); }
      else          { asm volatile("s_waitcnt vmcnt(0)" ::: "memory"); }
      FENCE256; __builtin_amdgcn_s_barrier(); FENCE256;

      if (j + 2 <= jmax) STAGEKV(j + 2, nxt2);

      const int buf = cur;
      cur  = (cur  == 2) ? 0 : cur  + 1;
      nxt2 = (nxt2 == 2) ? 0 : nxt2 + 1;

      const int kv0 = j * 64;
      if (kv0 > qw0 + 15) continue;   // wave-uniform: fully masked tile for this wave
                                      // (no barriers below -> safe divergence)

      f32x4 sacc[4] = {};
      #pragma unroll
      for (int nb = 0; nb < 4; ++nb) {
        int kvr = nb * 16 + l16;
        #pragma unroll
        for (int ks = 0; ks < 4; ++ks) {
          int dc2 = (ks * 4 + quad) ^ (kvr & 15);
          bf16x8 kb = *(const bf16x8*)&Ks[buf][(kvr * 16 + dc2) * 8];
          sacc[nb] = __builtin_amdgcn_mfma_f32_16x16x32_bf16(kb, qf[ks], sacc[nb], 0, 0, 0);
        }
      }

      float p[4][4];
      float smax = -1e30f;
      if (kv0 + 63 > qw0) {           // diagonal region: apply causal mask
        const int qg = qw0 + l16;
        #pragma unroll
        for (int nb = 0; nb < 4; ++nb)
          #pragma unroll
          for (int r = 0; r < 4; ++r) {
            float v = sacc[nb][r];
            if ((kv0 + nb * 16 + quad * 4 + r) > qg) v = -1e30f;
            p[nb][r] = v;
            smax = fmaxf(smax, v);
          }
      } else {
        #pragma unroll
        for (int nb = 0; nb < 4; ++nb)
          #pragma unroll
          for (int r = 0; r < 4; ++r) {
            float v = sacc[nb][r];
            p[nb][r] = v;
            smax = fmaxf(smax, v);
          }
      }
      smax = fmaxf(smax, __shfl_xor(smax, 16));
      smax = fmaxf(smax, __shfl_xor(smax, 32));

      const float mold = mrow;
      const unsigned long long grew = __ballot(smax > mold);
      const float mnew = fmaxf(mold, smax);
      mrow = mnew;

      float rs = 0.f;
      #pragma unroll
      for (int nb = 0; nb < 4; ++nb)
        #pragma unroll
        for (int r = 0; r < 4; ++r) {
          float pv = exp2f(p[nb][r] - mnew);
          p[nb][r] = pv;
          rs += pv;
        }
      rs += __shfl_xor(rs, 16);
      rs += __shfl_xor(rs, 32);

      unsigned short* pw = &Ps[wave][0];
      #pragma unroll
      for (int nb = 0; nb < 4; ++nb) {
        __hip_bfloat162 lo = __float22bfloat162_rn(make_float2(p[nb][0], p[nb][1]));
        __hip_bfloat162 hi = __float22bfloat162_rn(make_float2(p[nb][2], p[nb][3]));
        ushort4 w;
        w.x = *(unsigned short*)&lo.x; w.y = *(unsigned short*)&lo.y;
        w.z = *(unsigned short*)&hi.x; w.w = *(unsigned short*)&hi.y;
        *(ushort4*)&pw[l16 * 72 + nb * 16 + quad * 4] = w;
      }

      if (grew) {   // wave-uniform: some q-row's max increased -> rescale O and lrow
        float alpha = exp2f(mold - mnew);   // ==1 for rows that didn't grow
        lrow = lrow * alpha + rs;
        #pragma unroll
        for (int r = 0; r < 4; ++r) {
          float av = __shfl(alpha, quad * 4 + r, 16);
          #pragma unroll
          for (int db = 0; db < 8; ++db) o[db][r] *= av;
        }
      } else {
        lrow += rs;
      }

      asm volatile("s_waitcnt lgkmcnt(0)" ::: "memory");
      bf16x8 pa[2];
      #pragma unroll
      for (int ks2 = 0; ks2 < 2; ++ks2)
        pa[ks2] = *(const bf16x8*)&pw[l16 * 72 + ks2 * 32 + quad * 8];

      #pragma unroll
      for (int db = 0; db < 8; ++db) {
        int d = db * 16 + l16;
        #pragma unroll
        for (int ks2 = 0; ks2 < 2; ++ks2) {
          int dc = (ks2 * 4 + quad) ^ (d & 7);
          bf16x8 vb = *(const bf16x8*)&Vs[buf][(d * 8 + dc) * 8];
          o[db] = __builtin_amdgcn_mfma_f32_16x16x32_bf16(pa[ks2], vb, o[db], 0, 0, 0);
        }
      }
    }

    #pragma unroll
    for (int r = 0; r < 4; ++r) {
      float lr = __shfl(lrow, quad * 4 + r, 16);
      float inv = 1.0f / lr;
      size_t row = rowbase + qw0 + quad * 4 + r;
      #pragma unroll
      for (int db = 0; db < 8; ++db)
        outb[row * EMBED + hq + db * 16 + l16] = f2bf(o[db][r] * inv);
    }
    __syncthreads();  // all waves done with buffers before next half restages
  }
}

extern "C" void kernel_launch(void* const* d_in, const int* in_sizes, int n_in,
                              void* d_out, int out_size, void* d_ws, size_t ws_size,
                              hipStream_t stream) {
  const float* x    = (const float*)d_in[0];
  const float* Wqkv = (const float*)d_in[1];
  const float* bqkv = (const float*)d_in[2];
  const float* Wout = (const float*)d_in[3];
  const float* bout = (const float*)d_in[4];
  float* out = (float*)d_out;

  unsigned short* xb    = (unsigned short*)d_ws;
  unsigned short* wqkvT = xb    + (size_t)ROWS * EMBED;    // [6144][2048]
  unsigned short* woutT = wqkvT + (size_t)EMBED * QKVC;    // [2048][2048]
  unsigned short* qkb   = woutT + (size_t)EMBED * EMBED;   // [4096][4096] Q|K
  unsigned short* vtb   = qkb   + (size_t)ROWS * 4096;     // [32*128][2048] V^T
  unsigned short* attnb = vtb   + (size_t)32 * HDIM * SEQ; // [4096][2048]

  // fused prep: cast + both weight transposes (one launch instead of three)
  prep_kernel<<<dim3(24576), 256, 0, stream>>>(x, Wqkv, Wout, xb, wqkvT, woutT);

  // Q|K part: 256x256 8-phase kernel, grid 16x16 = 256 blocks = exactly 1 round
  gemm256_kernel<<<dim3((2 * EMBED / 256) * (ROWS / 256)), 512, 0, stream>>>(
      xb, wqkvT, bqkv, qkb, vtb, ROWS, 2 * EMBED, EMBED);

  // V part: proven 128x128 kernel, MODE 2 (BT/bias pre-offset to the V third)
  gemm_kernel<2><<<dim3(EMBED / 128, ROWS / 128), 256, 0, stream>>>(
      xb, wqkvT + (size_t)(2 * EMBED) * EMBED, bqkv + 2 * EMBED,
      nullptr, vtb, nullptr, ROWS, EMBED, EMBED);

  // attention: grid (32,8), 512 threads, balanced pair-loop, 114KB LDS
  attn_kernel<<<dim3(32, 8), 512, 0, stream>>>(qkb, vtb, attnb);

  gemm_kernel<1><<<dim3(EMBED / 128, ROWS / 128), 256, 0, stream>>>(
      attnb, woutT, bout, nullptr, nullptr, out, ROWS, EMBED, EMBED);
}